// Round 1
// baseline (1123.986 us; speedup 1.0000x reference)
//
#include <hip/hip_runtime.h>

#define NUM_NODES 10000
#define NUM_EDGES 640000
#define DIM 128

// ---------------------------------------------------------------------------
// Kernel 1: agg = x   (float4 copy)
// ---------------------------------------------------------------------------
__global__ void init_agg_kernel(const float* __restrict__ x, float* __restrict__ agg) {
    int i = blockIdx.x * blockDim.x + threadIdx.x;
    int n4 = NUM_NODES * DIM / 4;
    if (i < n4) {
        reinterpret_cast<float4*>(agg)[i] = reinterpret_cast<const float4*>(x)[i];
    }
}

// ---------------------------------------------------------------------------
// Kernel 2: for each edge e: agg[row[e], :] += x[col[e], :]
// 32 threads per edge; each thread handles 4 consecutive floats (float4 load,
// 4 scalar f32 atomics). x row reads are contiguous 512B per edge -> coalesced.
// ---------------------------------------------------------------------------
__global__ void scatter_add_kernel(const float* __restrict__ x,
                                   const int* __restrict__ ei,
                                   float* __restrict__ agg) {
    long long t = (long long)blockIdx.x * blockDim.x + threadIdx.x;
    int e = (int)(t >> 5);
    int sub = ((int)t & 31) << 2;   // 0,4,...,124
    if (e >= NUM_EDGES) return;
    int row = ei[2 * e];
    int col = ei[2 * e + 1];
    float4 v = *reinterpret_cast<const float4*>(x + (long long)col * DIM + sub);
    float* dst = agg + (long long)row * DIM + sub;
    atomicAdd(dst + 0, v.x);
    atomicAdd(dst + 1, v.y);
    atomicAdd(dst + 2, v.z);
    atomicAdd(dst + 3, v.w);
}

// ---------------------------------------------------------------------------
// Kernel 3: out = relu(agg @ W1 + b1) @ W2 + b2
// W1, W2, b1, b2 staged in LDS (129 KB) -> 1 block/CU. 512 threads = 4 rows
// per iteration; thread (r, j) computes column j of row r.
// LDS access: w1s[k*128+j] -> lanes j=0..63 hit banks 0..31 twice (free
// 2-way); as[r][k] is a wave broadcast (free).
// ---------------------------------------------------------------------------
__global__ __launch_bounds__(512) void fused_mlp_kernel(
        const float* __restrict__ agg,
        const float* __restrict__ W1, const float* __restrict__ b1,
        const float* __restrict__ W2, const float* __restrict__ b2,
        float* __restrict__ out) {
    __shared__ float w1s[DIM * DIM];
    __shared__ float w2s[DIM * DIM];
    __shared__ float b1s[DIM];
    __shared__ float b2s[DIM];
    __shared__ float as[4][DIM];
    __shared__ float hs[4][DIM];

    // stage weights (128 KB) once per block
    for (int i = threadIdx.x; i < DIM * DIM; i += blockDim.x) {
        w1s[i] = W1[i];
        w2s[i] = W2[i];
    }
    if (threadIdx.x < DIM) {
        b1s[threadIdx.x] = b1[threadIdx.x];
        b2s[threadIdx.x] = b2[threadIdx.x];
    }
    __syncthreads();

    const int r = threadIdx.x >> 7;    // 0..3
    const int j = threadIdx.x & 127;   // 0..127

    for (int base = blockIdx.x * 4; base < NUM_NODES; base += gridDim.x * 4) {
        int rowid = base + r;
        as[r][j] = (rowid < NUM_NODES) ? agg[(long long)rowid * DIM + j] : 0.0f;
        __syncthreads();

        float acc = b1s[j];
        #pragma unroll 8
        for (int k = 0; k < DIM; ++k)
            acc = fmaf(as[r][k], w1s[k * DIM + j], acc);
        float h = fmaxf(acc, 0.0f);
        hs[r][j] = h;
        __syncthreads();

        float acc2 = b2s[j];
        #pragma unroll 8
        for (int k = 0; k < DIM; ++k)
            acc2 = fmaf(hs[r][k], w2s[k * DIM + j], acc2);
        if (rowid < NUM_NODES)
            out[(long long)rowid * DIM + j] = acc2;
        __syncthreads();   // protect as/hs before next iteration
    }
}

// ---------------------------------------------------------------------------
extern "C" void kernel_launch(void* const* d_in, const int* in_sizes, int n_in,
                              void* d_out, int out_size, void* d_ws, size_t ws_size,
                              hipStream_t stream) {
    const float* x  = (const float*)d_in[0];
    const int*   ei = (const int*)d_in[1];
    const float* W1 = (const float*)d_in[2];
    const float* b1 = (const float*)d_in[3];
    const float* W2 = (const float*)d_in[4];
    const float* b2 = (const float*)d_in[5];
    float* out = (float*)d_out;

    const size_t agg_bytes = (size_t)NUM_NODES * DIM * sizeof(float);
    // agg lives in workspace; fall back to in-place on d_out if ws too small
    // (in-place is safe: each row is read before it is written, same block).
    float* agg = (ws_size >= agg_bytes) ? (float*)d_ws : out;

    // 1) agg = x
    {
        int n4 = NUM_NODES * DIM / 4;
        int threads = 256;
        int blocks = (n4 + threads - 1) / threads;
        init_agg_kernel<<<blocks, threads, 0, stream>>>(x, agg);
    }
    // 2) scatter-add over edges
    {
        long long total = (long long)NUM_EDGES * 32;
        int threads = 256;
        int blocks = (int)((total + threads - 1) / threads);
        scatter_add_kernel<<<blocks, threads, 0, stream>>>(x, ei, agg);
    }
    // 3) fused 2-layer MLP
    {
        fused_mlp_kernel<<<256, 512, 0, stream>>>(agg, W1, b1, W2, b2, out);
    }
}

// Round 2
// 171.254 us; speedup vs baseline: 6.5633x; 6.5633x over previous
//
#include <hip/hip_runtime.h>

#define NN  10000
#define NE  640000
#define DIM 128

// ---------------------------------------------------------------------------
// ws layout (ints):
//   deg    @ 0          (10240)   -- zeroed each call
//   fill   @ 10240      (10240)   -- zeroed each call
//   rowptr @ 20480      (10240)
//   colidx @ 30720      (640000)
// total = 670720 ints = 2,682,880 bytes. agg (5.12 MB) appended if it fits,
// else agg lives in d_out (in-place through the MLP is safe: each row's agg
// read happens in the same block iteration as its out write).
// ---------------------------------------------------------------------------
#define WS_DEG    0
#define WS_FILL   10240
#define WS_ROWPTR 20480
#define WS_COLIDX 30720
#define WS_INTS   (30720 + NE)

// ---------------------------------------------------------------------------
__global__ void zero_ints_kernel(int* __restrict__ p, int n) {
    int i = blockIdx.x * blockDim.x + threadIdx.x;
    if (i < n) p[i] = 0;
}

// count in-degree per destination row
__global__ void count_kernel(const int* __restrict__ ei, int* __restrict__ deg) {
    int e = blockIdx.x * blockDim.x + threadIdx.x;
    if (e < NE) atomicAdd(&deg[ei[2 * e]], 1);
}

// single-block exclusive scan of deg[0..NN) -> rowptr[0..NN]
__global__ __launch_bounds__(1024) void scan_kernel(const int* __restrict__ deg,
                                                    int* __restrict__ rowptr) {
    __shared__ int part[1024];
    const int t = threadIdx.x;
    const int base = t * 10;
    int local[10];
    int s = 0;
    #pragma unroll
    for (int i = 0; i < 10; ++i) {
        int v = (base + i < NN) ? deg[base + i] : 0;
        local[i] = s;
        s += v;
    }
    part[t] = s;
    __syncthreads();
    // Hillis-Steele inclusive scan over the 1024 partials
    for (int off = 1; off < 1024; off <<= 1) {
        int v = (t >= off) ? part[t - off] : 0;
        __syncthreads();
        part[t] += v;
        __syncthreads();
    }
    int ex = (t == 0) ? 0 : part[t - 1];
    #pragma unroll
    for (int i = 0; i < 10; ++i)
        if (base + i < NN) rowptr[base + i] = ex + local[i];
    if (t == 1023) rowptr[NN] = part[1023];
}

// scatter column indices into CSR order
__global__ void fill_kernel(const int* __restrict__ ei,
                            const int* __restrict__ rowptr,
                            int* __restrict__ fill,
                            int* __restrict__ colidx) {
    int e = blockIdx.x * blockDim.x + threadIdx.x;
    if (e < NE) {
        int r = ei[2 * e];
        int c = ei[2 * e + 1];
        int pos = rowptr[r] + atomicAdd(&fill[r], 1);
        colidx[pos] = c;
    }
}

// gather: agg[n,:] = x[n,:] + sum_{e in row n} x[colidx[e],:]
// one 128-thread block per node; thread j owns column j.
__global__ __launch_bounds__(128) void gather_kernel(const float* __restrict__ x,
                                                     const int* __restrict__ rowptr,
                                                     const int* __restrict__ colidx,
                                                     float* __restrict__ agg) {
    const int n = blockIdx.x;
    const int j = threadIdx.x;
    const int s = rowptr[n];
    const int e = rowptr[n + 1];
    float acc = x[(long long)n * DIM + j];
    float a0 = 0.f, a1 = 0.f, a2 = 0.f, a3 = 0.f;
    int k = s;
    for (; k + 4 <= e; k += 4) {
        int c0 = colidx[k + 0];
        int c1 = colidx[k + 1];
        int c2 = colidx[k + 2];
        int c3 = colidx[k + 3];
        a0 += x[(long long)c0 * DIM + j];
        a1 += x[(long long)c1 * DIM + j];
        a2 += x[(long long)c2 * DIM + j];
        a3 += x[(long long)c3 * DIM + j];
    }
    for (; k < e; ++k)
        acc += x[(long long)colidx[k] * DIM + j];
    acc += (a0 + a1) + (a2 + a3);
    agg[(long long)n * DIM + j] = acc;
}

// ---------------------------------------------------------------------------
// fallback scatter path (round-1), used only if ws is too small for CSR
// ---------------------------------------------------------------------------
__global__ void init_agg_kernel(const float* __restrict__ x, float* __restrict__ agg) {
    int i = blockIdx.x * blockDim.x + threadIdx.x;
    int n4 = NN * DIM / 4;
    if (i < n4)
        reinterpret_cast<float4*>(agg)[i] = reinterpret_cast<const float4*>(x)[i];
}

__global__ void scatter_add_kernel(const float* __restrict__ x,
                                   const int* __restrict__ ei,
                                   float* __restrict__ agg) {
    long long t = (long long)blockIdx.x * blockDim.x + threadIdx.x;
    int e = (int)(t >> 5);
    int sub = ((int)t & 31) << 2;
    if (e >= NE) return;
    int row = ei[2 * e];
    int col = ei[2 * e + 1];
    float4 v = *reinterpret_cast<const float4*>(x + (long long)col * DIM + sub);
    float* dst = agg + (long long)row * DIM + sub;
    atomicAdd(dst + 0, v.x);
    atomicAdd(dst + 1, v.y);
    atomicAdd(dst + 2, v.z);
    atomicAdd(dst + 3, v.w);
}

// ---------------------------------------------------------------------------
// fused 2-layer MLP: out = relu(agg @ W1 + b1) @ W2 + b2
// ---------------------------------------------------------------------------
__global__ __launch_bounds__(512) void fused_mlp_kernel(
        const float* __restrict__ agg,
        const float* __restrict__ W1, const float* __restrict__ b1,
        const float* __restrict__ W2, const float* __restrict__ b2,
        float* __restrict__ out) {
    __shared__ float w1s[DIM * DIM];
    __shared__ float w2s[DIM * DIM];
    __shared__ float b1s[DIM];
    __shared__ float b2s[DIM];
    __shared__ float as[4][DIM];
    __shared__ float hs[4][DIM];

    for (int i = threadIdx.x; i < DIM * DIM; i += blockDim.x) {
        w1s[i] = W1[i];
        w2s[i] = W2[i];
    }
    if (threadIdx.x < DIM) {
        b1s[threadIdx.x] = b1[threadIdx.x];
        b2s[threadIdx.x] = b2[threadIdx.x];
    }
    __syncthreads();

    const int r = threadIdx.x >> 7;
    const int j = threadIdx.x & 127;

    for (int base = blockIdx.x * 4; base < NN; base += gridDim.x * 4) {
        int rowid = base + r;
        as[r][j] = (rowid < NN) ? agg[(long long)rowid * DIM + j] : 0.0f;
        __syncthreads();

        float acc = b1s[j];
        #pragma unroll 8
        for (int k = 0; k < DIM; ++k)
            acc = fmaf(as[r][k], w1s[k * DIM + j], acc);
        hs[r][j] = fmaxf(acc, 0.0f);
        __syncthreads();

        float acc2 = b2s[j];
        #pragma unroll 8
        for (int k = 0; k < DIM; ++k)
            acc2 = fmaf(hs[r][k], w2s[k * DIM + j], acc2);
        if (rowid < NN)
            out[(long long)rowid * DIM + j] = acc2;
        __syncthreads();
    }
}

// ---------------------------------------------------------------------------
extern "C" void kernel_launch(void* const* d_in, const int* in_sizes, int n_in,
                              void* d_out, int out_size, void* d_ws, size_t ws_size,
                              hipStream_t stream) {
    const float* x  = (const float*)d_in[0];
    const int*   ei = (const int*)d_in[1];
    const float* W1 = (const float*)d_in[2];
    const float* b1 = (const float*)d_in[3];
    const float* W2 = (const float*)d_in[4];
    const float* b2 = (const float*)d_in[5];
    float* out = (float*)d_out;

    const size_t csr_bytes = (size_t)WS_INTS * sizeof(int);
    const size_t agg_bytes = (size_t)NN * DIM * sizeof(float);

    if (ws_size >= csr_bytes) {
        int* wsI    = (int*)d_ws;
        int* deg    = wsI + WS_DEG;
        int* fill   = wsI + WS_FILL;
        int* rowptr = wsI + WS_ROWPTR;
        int* colidx = wsI + WS_COLIDX;
        // agg in ws if it fits (after CSR), else in d_out (in-place safe)
        float* agg = (ws_size >= csr_bytes + agg_bytes)
                         ? (float*)((char*)d_ws + csr_bytes)
                         : out;

        zero_ints_kernel<<<(20480 + 255) / 256, 256, 0, stream>>>(deg, 20480); // deg+fill contiguous
        count_kernel<<<(NE + 255) / 256, 256, 0, stream>>>(ei, deg);
        scan_kernel<<<1, 1024, 0, stream>>>(deg, rowptr);
        fill_kernel<<<(NE + 255) / 256, 256, 0, stream>>>(ei, rowptr, fill, colidx);
        gather_kernel<<<NN, 128, 0, stream>>>(x, rowptr, colidx, agg);
        fused_mlp_kernel<<<256, 512, 0, stream>>>(agg, W1, b1, W2, b2, out);
    } else {
        // fallback: atomic scatter path
        float* agg = (ws_size >= agg_bytes) ? (float*)d_ws : out;
        int n4 = NN * DIM / 4;
        init_agg_kernel<<<(n4 + 255) / 256, 256, 0, stream>>>(x, agg);
        long long total = (long long)NE * 32;
        scatter_add_kernel<<<(int)((total + 255) / 256), 256, 0, stream>>>(x, ei, agg);
        fused_mlp_kernel<<<256, 512, 0, stream>>>(agg, W1, b1, W2, b2, out);
    }
}

// Round 3
// 93.117 us; speedup vs baseline: 12.0706x; 1.8391x over previous
//
#include <hip/hip_runtime.h>

#define NN  10000
#define NE  640000
#define DIM 128

typedef __attribute__((ext_vector_type(8))) short bf16x8;
typedef __attribute__((ext_vector_type(4))) float f32x4;

__device__ inline unsigned short f2bf(float f) {
    unsigned u = __builtin_bit_cast(unsigned, f);
    unsigned r = (u + 0x7fffu + ((u >> 16) & 1u)) >> 16;
    return (unsigned short)r;
}

// ===========================================================================
// PRIMARY PATH (ws >= 5,268,480 B)
// ws layout (ints unless noted):
//   rowptr @ 0        (10496)
//   deg    @ 10496    (10240)      } overlaid by agg_bf16 (2.56 MB) at
//   rank   @ 20736    (640000)     } gather time (deg/rank dead by then)
//   colidx @ 660736   (640000)
//   W1p    @ byte 5,202,944 (32768 B, bf16 MFMA-frag order)
//   W2p    @ byte 5,235,712 (32768 B)
// ===========================================================================

// --- pack W1/W2 into MFMA B-frag order (bf16) + zero deg --------------------
// B-frag layout for mfma_f32_16x16x32_bf16: lane l, elem e holds
// B[kt*32 + (l>>4)*8 + e][nt*16 + (l&15)]; packed so a frag is 16 contiguous B.
__global__ void pack_zero_kernel(const float* __restrict__ W1,
                                 const float* __restrict__ W2,
                                 unsigned short* __restrict__ W1p,
                                 unsigned short* __restrict__ W2p,
                                 int* __restrict__ deg) {
    int id = blockIdx.x * 256 + threadIdx.x;
    if (id < 32768) {
        const float* W = (id < 16384) ? W1 : W2;
        unsigned short* Wp = (id < 16384) ? W1p : W2p;
        int f = id & 16383;
        int e = f & 7, lane = (f >> 3) & 63, kt = (f >> 9) & 3, nt = f >> 11;
        int kglob = kt * 32 + (lane >> 4) * 8 + e;
        int jglob = nt * 16 + (lane & 15);
        Wp[f] = f2bf(W[kglob * DIM + jglob]);
    } else if (id < 32768 + 10240) {
        deg[id - 32768] = 0;
    }
}

// --- in-degree count; rank[e] = arrival order within its row ----------------
__global__ void count_rank_kernel(const int* __restrict__ ei,
                                  int* __restrict__ deg,
                                  int* __restrict__ rank) {
    int e = blockIdx.x * 256 + threadIdx.x;
    if (e < NE) {
        int r = ei[2 * e];
        rank[e] = atomicAdd(&deg[r], 1);
    }
}

// --- single-block exclusive scan, shuffle-based (2 barriers) ----------------
__global__ __launch_bounds__(1024) void scan_kernel(const int* __restrict__ deg,
                                                    int* __restrict__ rowptr) {
    __shared__ int wtot[16];
    const int t = threadIdx.x;
    const int base = t * 10;
    int local[10];
    int s = 0;
    #pragma unroll
    for (int i = 0; i < 10; ++i) {
        int v = (base + i < NN) ? deg[base + i] : 0;
        local[i] = s;
        s += v;
    }
    const int mySum = s;
    #pragma unroll
    for (int off = 1; off < 64; off <<= 1) {
        int v = __shfl_up(s, (unsigned)off, 64);
        if ((t & 63) >= off) s += v;
    }
    if ((t & 63) == 63) wtot[t >> 6] = s;
    __syncthreads();
    if (t == 0) {
        int run = 0;
        #pragma unroll
        for (int i = 0; i < 16; ++i) { int v = wtot[i]; wtot[i] = run; run += v; }
    }
    __syncthreads();
    const int ex = wtot[t >> 6] + (s - mySum);
    #pragma unroll
    for (int i = 0; i < 10; ++i)
        if (base + i < NN) rowptr[base + i] = ex + local[i];
    if (t == 1023) rowptr[NN] = ex + mySum;
}

// --- fill CSR columns: no atomics (rank precomputed) ------------------------
__global__ void fill_rank_kernel(const int* __restrict__ ei,
                                 const int* __restrict__ rank,
                                 const int* __restrict__ rowptr,
                                 int* __restrict__ colidx) {
    int e = blockIdx.x * 256 + threadIdx.x;
    if (e < NE) {
        int r = ei[2 * e];
        int c = ei[2 * e + 1];
        colidx[rowptr[r] + rank[e]] = c;
    }
}

// --- gather: agg_bf16[n,:] = bf16(x[n,:] + sum_neighbors x[c,:]) ------------
// 32 lanes per node, float4 per lane, int4 colidx loads, 4 accumulators.
__global__ __launch_bounds__(256) void gather_bf16_kernel(
        const float* __restrict__ x,
        const int* __restrict__ rowptr,
        const int* __restrict__ colidx,
        unsigned short* __restrict__ aggb) {
    const int node = blockIdx.x * 8 + (threadIdx.x >> 5);
    const int sub  = threadIdx.x & 31;
    if (node >= NN) return;
    const int s = rowptr[node];
    const int e = rowptr[node + 1];

    float4 acc = *(reinterpret_cast<const float4*>(x + (size_t)node * DIM) + sub);
    float4 a1 = {0.f, 0.f, 0.f, 0.f}, a2 = {0.f, 0.f, 0.f, 0.f}, a3 = {0.f, 0.f, 0.f, 0.f};

    int k = s;
    for (; (k & 3) != 0 && k < e; ++k) {
        float4 v = *(reinterpret_cast<const float4*>(x + (size_t)colidx[k] * DIM) + sub);
        acc.x += v.x; acc.y += v.y; acc.z += v.z; acc.w += v.w;
    }
    for (; k + 4 <= e; k += 4) {
        int4 c = *reinterpret_cast<const int4*>(colidx + k);
        float4 v0 = *(reinterpret_cast<const float4*>(x + (size_t)c.x * DIM) + sub);
        float4 v1 = *(reinterpret_cast<const float4*>(x + (size_t)c.y * DIM) + sub);
        float4 v2 = *(reinterpret_cast<const float4*>(x + (size_t)c.z * DIM) + sub);
        float4 v3 = *(reinterpret_cast<const float4*>(x + (size_t)c.w * DIM) + sub);
        acc.x += v0.x; acc.y += v0.y; acc.z += v0.z; acc.w += v0.w;
        a1.x += v1.x; a1.y += v1.y; a1.z += v1.z; a1.w += v1.w;
        a2.x += v2.x; a2.y += v2.y; a2.z += v2.z; a2.w += v2.w;
        a3.x += v3.x; a3.y += v3.y; a3.z += v3.z; a3.w += v3.w;
    }
    for (; k < e; ++k) {
        float4 v = *(reinterpret_cast<const float4*>(x + (size_t)colidx[k] * DIM) + sub);
        acc.x += v.x; acc.y += v.y; acc.z += v.z; acc.w += v.w;
    }
    acc.x += (a1.x + a2.x) + a3.x;
    acc.y += (a1.y + a2.y) + a3.y;
    acc.z += (a1.z + a2.z) + a3.z;
    acc.w += (a1.w + a2.w) + a3.w;

    ushort4 pk;
    pk.x = f2bf(acc.x); pk.y = f2bf(acc.y); pk.z = f2bf(acc.z); pk.w = f2bf(acc.w);
    *reinterpret_cast<ushort4*>(aggb + (size_t)node * DIM + sub * 4) = pk;
}

// --- fused 2-layer MLP on MFMA ----------------------------------------------
// Per wave: one 16-row tile. A-frag: lane l elem e = A[l&15][kt*32+(l>>4)*8+e].
// D-frag:  lane l reg r  = D[(l>>4)*4+r][l&15].
// Layer1 D -> bf16 -> per-wave padded LDS -> layer2 A-frags. No __syncthreads.
__global__ __launch_bounds__(256) void mlp_mfma_kernel(
        const unsigned short* __restrict__ aggb,
        const unsigned short* __restrict__ W1p,
        const unsigned short* __restrict__ W2p,
        const float* __restrict__ b1,
        const float* __restrict__ b2,
        float* __restrict__ out) {
    __shared__ __align__(16) unsigned short hbuf[4][16][136]; // +8 pad: bank spread

    const int wid  = threadIdx.x >> 6;
    const int lane = threadIdx.x & 63;
    const int t = blockIdx.x * 4 + wid;
    if (t >= NN / 16) return;            // 625 tiles
    const int row0 = t * 16;
    const int r16  = lane & 15;
    const int kg   = lane >> 4;
    const int drow = kg * 4;

    // layer-1 A frags from agg_bf16
    bf16x8 af[4];
    #pragma unroll
    for (int kt = 0; kt < 4; ++kt)
        af[kt] = *reinterpret_cast<const bf16x8*>(
            aggb + (size_t)(row0 + r16) * DIM + kt * 32 + kg * 8);

    const f32x4 zero = {0.f, 0.f, 0.f, 0.f};
    f32x4 acc[8];
    #pragma unroll
    for (int nt = 0; nt < 8; ++nt) acc[nt] = zero;

    #pragma unroll
    for (int kt = 0; kt < 4; ++kt) {
        #pragma unroll
        for (int nt = 0; nt < 8; ++nt) {
            bf16x8 w = *reinterpret_cast<const bf16x8*>(
                W1p + ((nt * 4 + kt) * 64 + lane) * 8);
            acc[nt] = __builtin_amdgcn_mfma_f32_16x16x32_bf16(af[kt], w, acc[nt], 0, 0, 0);
        }
    }

    // epilogue 1: bias + relu -> bf16 -> hbuf (D layout)
    #pragma unroll
    for (int nt = 0; nt < 8; ++nt) {
        float bv = b1[nt * 16 + r16];
        #pragma unroll
        for (int r = 0; r < 4; ++r) {
            float h = fmaxf(acc[nt][r] + bv, 0.0f);
            hbuf[wid][drow + r][nt * 16 + r16] = f2bf(h);
        }
    }

    // layer-2 A frags from hbuf (A layout; same-wave LDS, compiler orders)
    bf16x8 hf[4];
    #pragma unroll
    for (int kt = 0; kt < 4; ++kt)
        hf[kt] = *reinterpret_cast<const bf16x8*>(&hbuf[wid][r16][kt * 32 + kg * 8]);

    f32x4 acc2[8];
    #pragma unroll
    for (int nt = 0; nt < 8; ++nt) acc2[nt] = zero;

    #pragma unroll
    for (int kt = 0; kt < 4; ++kt) {
        #pragma unroll
        for (int nt = 0; nt < 8; ++nt) {
            bf16x8 w = *reinterpret_cast<const bf16x8*>(
                W2p + ((nt * 4 + kt) * 64 + lane) * 8);
            acc2[nt] = __builtin_amdgcn_mfma_f32_16x16x32_bf16(hf[kt], w, acc2[nt], 0, 0, 0);
        }
    }

    // epilogue 2: bias, f32 store
    #pragma unroll
    for (int nt = 0; nt < 8; ++nt) {
        float bv = b2[nt * 16 + r16];
        #pragma unroll
        for (int r = 0; r < 4; ++r)
            out[(size_t)(row0 + drow + r) * DIM + nt * 16 + r16] = acc2[nt][r] + bv;
    }
}

// ===========================================================================
// FALLBACK PATH (round-2 proven kernels; ws >= 2,682,880 B)
// ===========================================================================
__global__ void fb_zero_kernel(int* __restrict__ p, int n) {
    int i = blockIdx.x * blockDim.x + threadIdx.x;
    if (i < n) p[i] = 0;
}
__global__ void fb_count_kernel(const int* __restrict__ ei, int* __restrict__ deg) {
    int e = blockIdx.x * blockDim.x + threadIdx.x;
    if (e < NE) atomicAdd(&deg[ei[2 * e]], 1);
}
__global__ void fb_fill_kernel(const int* __restrict__ ei, const int* __restrict__ rowptr,
                               int* __restrict__ fill, int* __restrict__ colidx) {
    int e = blockIdx.x * blockDim.x + threadIdx.x;
    if (e < NE) {
        int r = ei[2 * e], c = ei[2 * e + 1];
        colidx[rowptr[r] + atomicAdd(&fill[r], 1)] = c;
    }
}
__global__ __launch_bounds__(128) void fb_gather_kernel(const float* __restrict__ x,
                                                        const int* __restrict__ rowptr,
                                                        const int* __restrict__ colidx,
                                                        float* __restrict__ agg) {
    const int n = blockIdx.x, j = threadIdx.x;
    const int s = rowptr[n], e = rowptr[n + 1];
    float acc = x[(size_t)n * DIM + j];
    float a0 = 0.f, a1 = 0.f, a2 = 0.f, a3 = 0.f;
    int k = s;
    for (; k + 4 <= e; k += 4) {
        a0 += x[(size_t)colidx[k + 0] * DIM + j];
        a1 += x[(size_t)colidx[k + 1] * DIM + j];
        a2 += x[(size_t)colidx[k + 2] * DIM + j];
        a3 += x[(size_t)colidx[k + 3] * DIM + j];
    }
    for (; k < e; ++k) acc += x[(size_t)colidx[k] * DIM + j];
    agg[(size_t)n * DIM + j] = acc + (a0 + a1) + (a2 + a3);
}
__global__ __launch_bounds__(512) void fb_mlp_kernel(
        const float* __restrict__ agg,
        const float* __restrict__ W1, const float* __restrict__ b1,
        const float* __restrict__ W2, const float* __restrict__ b2,
        float* __restrict__ out) {
    __shared__ float w1s[DIM * DIM];
    __shared__ float w2s[DIM * DIM];
    __shared__ float b1s[DIM], b2s[DIM];
    __shared__ float as[4][DIM], hs[4][DIM];
    for (int i = threadIdx.x; i < DIM * DIM; i += blockDim.x) { w1s[i] = W1[i]; w2s[i] = W2[i]; }
    if (threadIdx.x < DIM) { b1s[threadIdx.x] = b1[threadIdx.x]; b2s[threadIdx.x] = b2[threadIdx.x]; }
    __syncthreads();
    const int r = threadIdx.x >> 7, j = threadIdx.x & 127;
    for (int base = blockIdx.x * 4; base < NN; base += gridDim.x * 4) {
        int rowid = base + r;
        as[r][j] = (rowid < NN) ? agg[(size_t)rowid * DIM + j] : 0.0f;
        __syncthreads();
        float acc = b1s[j];
        #pragma unroll 8
        for (int k = 0; k < DIM; ++k) acc = fmaf(as[r][k], w1s[k * DIM + j], acc);
        hs[r][j] = fmaxf(acc, 0.0f);
        __syncthreads();
        float acc2 = b2s[j];
        #pragma unroll 8
        for (int k = 0; k < DIM; ++k) acc2 = fmaf(hs[r][k], w2s[k * DIM + j], acc2);
        if (rowid < NN) out[(size_t)rowid * DIM + j] = acc2;
        __syncthreads();
    }
}

// ===========================================================================
extern "C" void kernel_launch(void* const* d_in, const int* in_sizes, int n_in,
                              void* d_out, int out_size, void* d_ws, size_t ws_size,
                              hipStream_t stream) {
    const float* x  = (const float*)d_in[0];
    const int*   ei = (const int*)d_in[1];
    const float* W1 = (const float*)d_in[2];
    const float* b1 = (const float*)d_in[3];
    const float* W2 = (const float*)d_in[4];
    const float* b2 = (const float*)d_in[5];
    float* out = (float*)d_out;

    const size_t need_primary = 5268480;

    if (ws_size >= need_primary) {
        int* rowptr = (int*)d_ws;                       // 10496 ints
        int* deg    = rowptr + 10496;                   // 10240 ints
        int* rank   = deg + 10240;                      // 640000 ints
        unsigned short* aggb = (unsigned short*)deg;    // overlays deg+rank (2.56 MB)
        int* colidx = rank + 640000;                    // 640000 ints
        unsigned short* W1p = (unsigned short*)(colidx + 640000);
        unsigned short* W2p = W1p + 16384;

        pack_zero_kernel<<<(43008 + 255) / 256, 256, 0, stream>>>(W1, W2, W1p, W2p, deg);
        count_rank_kernel<<<(NE + 255) / 256, 256, 0, stream>>>(ei, deg, rank);
        scan_kernel<<<1, 1024, 0, stream>>>(deg, rowptr);
        fill_rank_kernel<<<(NE + 255) / 256, 256, 0, stream>>>(ei, rank, rowptr, colidx);
        gather_bf16_kernel<<<NN / 8, 256, 0, stream>>>(x, rowptr, colidx, aggb);
        mlp_mfma_kernel<<<(NN / 16 + 3) / 4, 256, 0, stream>>>(aggb, W1p, W2p, b1, b2, out);
    } else {
        // fallback: round-2 f32 path (csr 2.68 MB; agg in ws if it fits, else d_out)
        int* wsI    = (int*)d_ws;
        int* deg    = wsI;
        int* fillc  = wsI + 10240;
        int* rowptr = wsI + 20480;
        int* colidx = wsI + 30720;
        const size_t csr_bytes = (size_t)(30720 + NE) * sizeof(int);
        const size_t agg_bytes = (size_t)NN * DIM * sizeof(float);
        float* agg = (ws_size >= csr_bytes + agg_bytes)
                         ? (float*)((char*)d_ws + csr_bytes) : out;

        fb_zero_kernel<<<(20480 + 255) / 256, 256, 0, stream>>>(deg, 20480);
        fb_count_kernel<<<(NE + 255) / 256, 256, 0, stream>>>(ei, deg);
        scan_kernel<<<1, 1024, 0, stream>>>(deg, rowptr);
        fb_fill_kernel<<<(NE + 255) / 256, 256, 0, stream>>>(ei, rowptr, fillc, colidx);
        fb_gather_kernel<<<NN, 128, 0, stream>>>(x, rowptr, colidx, agg);
        fb_mlp_kernel<<<256, 512, 0, stream>>>(agg, W1, b1, W2, b2, out);
    }
}